// Round 1
// baseline (169.941 us; speedup 1.0000x reference)
//
#include <hip/hip_runtime.h>
#include <hip/hip_bf16.h>

// ---------------------------------------------------------------------------
// HiddenEdgeDistanceMLP on MI355X (gfx950)
//
// reference:  s = s_lig[l] + s_poc[p]          [E,256]
//             h1 = silu(s @ W1.T + b1)         [E,128]
//             h2 = silu(h1 @ W2.T + b2)        [E,64]
//             out = relu(h2 @ W3.T + b3)       [E]
//
// v13 (R0 of this session): FUSED single kernel.
//   Theory: edge_kernel=50us but dur_us=138 -> ~88us lives in proj_kernel +
//   the serialized Z round-trip (12.6MB write + 14.5MB fetch) + launch gap.
//   Each edge block only needs 32 Z-rows (16 ligand, 16 pocket) x 128 cols;
//   compute them IN-BLOCK with MFMA (pipe was 92% idle) and pass through LDS.
//   Extra cost: per-wave W1 f2bf B-frags + X hi/lo pack_split (~6-9us VALU
//   across kernel, W1/X re-reads hit L2/L3); saved: proj wall time, Z HBM
//   round-trip, inter-kernel serialization.
//   Numerics BITWISE identical to v12: same pack_split A hi/lo, same f2bf-RNE
//   W1 frags, same per-accumulator MFMA order (per-ks hi then lo), b1 folded
//   after accumulation into ligand rows only. Expect absmax == 0.001953125.
// v12 mechanisms kept: 2-atoms-per-K-pass (shared W2-frag + pocket reads),
//   b2 folded into acc init, single rhu-bf16 h1 + 1 MFMA/nt, W2 B-frags
//   fragment-ordered in LDS, DPP rowsum, perm packing, no min-waves bound
//   (R3: VGPR cliff -> spills). Prefetch machinery dropped: ligand rows now
//   come from LDS (~120cy), not global.
// ---------------------------------------------------------------------------

#define B_CPLX   128
#define NLB      32
#define NPB      160
#define SDIM     256
#define H1DIM    128
#define NL_TOT   (B_CPLX * NLB)         // 4096
#define NP_TOT   (B_CPLX * NPB)         // 20480
#define E_TOT    (B_CPLX * NLB * NPB)   // 655360

#define JT_CHUNK 16                     // pocket rows per block
#define ZP_STRIDE 132                   // 128 + 4 f32 pad

typedef __bf16 bf16x8 __attribute__((ext_vector_type(8)));
typedef unsigned short ushortx8 __attribute__((ext_vector_type(8)));
typedef unsigned short ushortx4 __attribute__((ext_vector_type(4)));
typedef unsigned uintx4 __attribute__((ext_vector_type(4)));
typedef float f32x4 __attribute__((ext_vector_type(4)));

__device__ __forceinline__ unsigned short f2bf(float f) {
    unsigned u = __builtin_bit_cast(unsigned, f);
    u += 0x7FFFu + ((u >> 16) & 1u);          // round-to-nearest-even
    return (unsigned short)(u >> 16);
}

// v_perm_b32: pack hi16(x0) low, hi16(x1) high (1 op)
__device__ __forceinline__ unsigned perm_hi16u(unsigned u0, unsigned u1) {
    return __builtin_amdgcn_perm(u1, u0, 0x07060302u);
}

// round-half-up bf16 pair pack: bitpattern + 0x8000 then take hi16.
__device__ __forceinline__ unsigned pack2_rhu(float x0, float x1) {
    unsigned u0 = __builtin_bit_cast(unsigned, x0) + 0x8000u;
    unsigned u1 = __builtin_bit_cast(unsigned, x1) + 0x8000u;
    return perm_hi16u(u0, u1);
}

__device__ __forceinline__ bf16x8 pack8_rhu(const float* x) {
    uintx4 h;
#pragma unroll
    for (int j = 0; j < 4; ++j) h[j] = pack2_rhu(x[2 * j], x[2 * j + 1]);
    return __builtin_bit_cast(bf16x8, h);
}

// hi/lo exact split (proj phase only): hi = trunc bf16, lo = bf16(x - hi)
__device__ __forceinline__ void pack_split(const float* x, bf16x8& hi, bf16x8& lo) {
    uintx4 h, l;
#pragma unroll
    for (int j = 0; j < 4; ++j) {
        float x0 = x[2 * j], x1 = x[2 * j + 1];
        unsigned u0 = __builtin_bit_cast(unsigned, x0);
        unsigned u1 = __builtin_bit_cast(unsigned, x1);
        h[j] = perm_hi16u(u0, u1);
        float hf0 = __builtin_bit_cast(float, u0 & 0xFFFF0000u);
        float hf1 = __builtin_bit_cast(float, u1 & 0xFFFF0000u);
        l[j] = pack2_rhu(x0 - hf0, x1 - hf1);
    }
    hi = __builtin_bit_cast(bf16x8, h);
    lo = __builtin_bit_cast(bf16x8, l);
}

__device__ __forceinline__ float fast_silu(float x) {
    return x * __builtin_amdgcn_rcpf(1.0f + __expf(-x));
}

// full-rate 16-lane row reduction: v_add_f32 + dpp row_ror 1,2,4,8
__device__ __forceinline__ float rowsum16(float s) {
    int b;
    b = __builtin_bit_cast(int, s);
    b = __builtin_amdgcn_update_dpp(b, b, 0x121, 0xF, 0xF, false);  // ror:1
    s += __builtin_bit_cast(float, b);
    b = __builtin_bit_cast(int, s);
    b = __builtin_amdgcn_update_dpp(b, b, 0x122, 0xF, 0xF, false);  // ror:2
    s += __builtin_bit_cast(float, b);
    b = __builtin_bit_cast(int, s);
    b = __builtin_amdgcn_update_dpp(b, b, 0x124, 0xF, 0xF, false);  // ror:4
    s += __builtin_bit_cast(float, b);
    b = __builtin_bit_cast(int, s);
    b = __builtin_amdgcn_update_dpp(b, b, 0x128, 0xF, 0xF, false);  // ror:8
    s += __builtin_bit_cast(float, b);
    return s;
}

// ---------------------------------------------------------------------------
// Fused kernel: block = (complex b, 16-pocket chunk jt, atom-half ih).
//   Phase A: stage W2 bf16 frags in LDS (as v12).
//   Phase B (proj): each wave owns 32 of 128 N-cols; computes Z for the
//     block's 16 ligand atoms and 16 pocket rows via hi/lo-split MFMA,
//     writes f32 results to zl/zp LDS (b1 folded into zl).
//   Phase C (edge): identical to v12 edge, ligand rows from zl LDS.
// ---------------------------------------------------------------------------
__global__ __launch_bounds__(256) void fused_kernel(
    const float* __restrict__ s_lig, const float* __restrict__ s_poc,
    const float* __restrict__ W1,    const float* __restrict__ b1,
    const float* __restrict__ W2,    const float* __restrict__ b2,
    const float* __restrict__ W3,    const float* __restrict__ b3,
    float* __restrict__ out)
{
    __shared__ float zp[JT_CHUNK * ZP_STRIDE];            // 8.4 KB pocket Z
    __shared__ float zl[JT_CHUNK * ZP_STRIDE];            // 8.4 KB ligand Z
    __shared__ unsigned short w2s[16 * 64 * 8];           // 16 KB frag-ordered

    const int tid = threadIdx.x;
    const int bid = blockIdx.x;
    const int b   = bid / 20;
    const int rem = bid - b * 20;
    const int jt  = rem >> 1;                     // 0..9
    const int ih  = rem & 1;                      // atom half

    const int lane = tid & 63;
    const int widx = tid >> 6;
    const int c    = lane & 15;
    const int q    = lane >> 4;

    // ---- Phase A: stage W2 as bf16 B-fragments, fragment-ordered ----
    {
#pragma unroll
        for (int s = 0; s < 4; ++s) {
            const int slot   = tid + s * 256;             // 0..1023
            const int lane_s = slot & 63;
            const int chunk  = slot >> 6;
            const int nt     = chunk >> 2;
            const int ks     = chunk & 3;
            const int n      = nt * 16 + (lane_s & 15);
            const int k0     = ks * 32 + (lane_s >> 4) * 8;
            const float* wsrc = W2 + (size_t)n * H1DIM + k0;
            f32x4 wa = *(const f32x4*)wsrc;
            f32x4 wb = *(const f32x4*)(wsrc + 4);
            float wv[8] = {wa[0], wa[1], wa[2], wa[3], wb[0], wb[1], wb[2], wb[3]};
            ushortx8 us;
#pragma unroll
            for (int j = 0; j < 8; ++j) us[j] = f2bf(wv[j]);   // RNE for weights
            *(ushortx8*)(&w2s[slot * 8]) = us;
        }
    }

    // ---- Phase B: in-block projection -> zl, zp ----
    {
        // A rows (M=16): lane c picks the row, q picks the K sub-chunk
        const float* xlr = s_lig + (size_t)(b * NLB + ih * 16 + c) * SDIM;
        const float* xpr = s_poc + (size_t)(b * NPB + jt * JT_CHUNK + c) * SDIM;
        // B rows: wave widx owns n in [widx*32, widx*32+32)
        const float* w1a = W1 + (size_t)(widx * 32 + c) * SDIM;
        const float* w1b = w1a + (size_t)16 * SDIM;

        f32x4 aP0 = (f32x4){0.f, 0.f, 0.f, 0.f};
        f32x4 aP1 = (f32x4){0.f, 0.f, 0.f, 0.f};
        f32x4 aL0 = (f32x4){0.f, 0.f, 0.f, 0.f};
        f32x4 aL1 = (f32x4){0.f, 0.f, 0.f, 0.f};

#pragma unroll
        for (int ks = 0; ks < 8; ++ks) {          // K = 256 = 8 x 32
            const int k0 = ks * 32 + q * 8;
            // B fragments (f2bf RNE — bitwise same values as v12's w1s)
            f32x4 wa0 = *(const f32x4*)(w1a + k0);
            f32x4 wa1 = *(const f32x4*)(w1a + k0 + 4);
            f32x4 wb0 = *(const f32x4*)(w1b + k0);
            f32x4 wb1 = *(const f32x4*)(w1b + k0 + 4);
            ushortx8 u0, u1;
#pragma unroll
            for (int j = 0; j < 4; ++j) {
                u0[j]     = f2bf(wa0[j]);
                u0[4 + j] = f2bf(wa1[j]);
                u1[j]     = f2bf(wb0[j]);
                u1[4 + j] = f2bf(wb1[j]);
            }
            const bf16x8 bfr0 = __builtin_bit_cast(bf16x8, u0);
            const bf16x8 bfr1 = __builtin_bit_cast(bf16x8, u1);
            // A fragments, hi/lo exact split (as v12 proj)
            f32x4 xa = *(const f32x4*)(xlr + k0);
            f32x4 xb = *(const f32x4*)(xlr + k0 + 4);
            float xv[8] = {xa[0], xa[1], xa[2], xa[3], xb[0], xb[1], xb[2], xb[3]};
            bf16x8 lhi, llo;
            pack_split(xv, lhi, llo);
            f32x4 pa = *(const f32x4*)(xpr + k0);
            f32x4 pb = *(const f32x4*)(xpr + k0 + 4);
            float pv[8] = {pa[0], pa[1], pa[2], pa[3], pb[0], pb[1], pb[2], pb[3]};
            bf16x8 phi, plo;
            pack_split(pv, phi, plo);

            // hi pass then lo pass (per-accumulator order identical to v12)
            aP0 = __builtin_amdgcn_mfma_f32_16x16x32_bf16(phi, bfr0, aP0, 0, 0, 0);
            aP1 = __builtin_amdgcn_mfma_f32_16x16x32_bf16(phi, bfr1, aP1, 0, 0, 0);
            aL0 = __builtin_amdgcn_mfma_f32_16x16x32_bf16(lhi, bfr0, aL0, 0, 0, 0);
            aL1 = __builtin_amdgcn_mfma_f32_16x16x32_bf16(lhi, bfr1, aL1, 0, 0, 0);
            aP0 = __builtin_amdgcn_mfma_f32_16x16x32_bf16(plo, bfr0, aP0, 0, 0, 0);
            aP1 = __builtin_amdgcn_mfma_f32_16x16x32_bf16(plo, bfr1, aP1, 0, 0, 0);
            aL0 = __builtin_amdgcn_mfma_f32_16x16x32_bf16(llo, bfr0, aL0, 0, 0, 0);
            aL1 = __builtin_amdgcn_mfma_f32_16x16x32_bf16(llo, bfr1, aL1, 0, 0, 0);
        }

        // D layout: col n' = lane&15, row m = q*4 + r. Fold b1 into zl only.
        const float b10 = b1[widx * 32 + c];
        const float b11 = b1[widx * 32 + 16 + c];
#pragma unroll
        for (int r = 0; r < 4; ++r) {
            const int row = q * 4 + r;
            zp[row * ZP_STRIDE + widx * 32 + c]      = aP0[r];
            zp[row * ZP_STRIDE + widx * 32 + 16 + c] = aP1[r];
            zl[row * ZP_STRIDE + widx * 32 + c]      = aL0[r] + b10;
            zl[row * ZP_STRIDE + widx * 32 + 16 + c] = aL1[r] + b11;
        }
    }

    float b2f[4], w3f[4];
#pragma unroll
    for (int nt = 0; nt < 4; ++nt) {
        b2f[nt] = b2[nt * 16 + c];
        w3f[nt] = W3[nt * 16 + c];
    }
    const float b3v = b3[0];

    __syncthreads();

    // ---- Phase C: edge MLP (identical math to v12) ----
    const float* prow = &zp[c * ZP_STRIDE];
    const unsigned short* wbase = &w2s[lane * 8];          // + chunk*512 ushorts

    const int a0l = widx * 4;                      // wave's first LOCAL atom

#pragma unroll
    for (int pair = 0; pair < 2; ++pair) {
        const int i0 = a0l + pair * 2;             // local atoms i0, i0+1

        // ligand rows from zl LDS (replaces v12's global loads + prefetch)
        const float* lr0 = &zl[i0 * ZP_STRIDE];
        f32x4 lgA[4][2], lgB[4][2];
#pragma unroll
        for (int ks = 0; ks < 4; ++ks) {
            const int k0 = ks * 32 + q * 8;
            lgA[ks][0] = *(const f32x4*)(lr0 + k0);
            lgA[ks][1] = *(const f32x4*)(lr0 + k0 + 4);
            lgB[ks][0] = *(const f32x4*)(lr0 + ZP_STRIDE + k0);
            lgB[ks][1] = *(const f32x4*)(lr0 + ZP_STRIDE + k0 + 4);
        }

        // b2 folded into acc init
        f32x4 acc0[4], acc1[4];
#pragma unroll
        for (int nt = 0; nt < 4; ++nt) {
            const float bb = b2f[nt];
            acc0[nt] = (f32x4){bb, bb, bb, bb};
            acc1[nt] = (f32x4){bb, bb, bb, bb};
        }

#pragma unroll
        for (int ks = 0; ks < 4; ++ks) {           // K = 128 = 4 x 32
            const int k0 = ks * 32 + q * 8;
            bf16x8 bfr[4];
#pragma unroll
            for (int nt = 0; nt < 4; ++nt)         // conflict-free ds_read_b128
                bfr[nt] = *(const bf16x8*)(wbase + (nt * 4 + ks) * 512);
            f32x4 pa = *(const f32x4*)(prow + k0);
            f32x4 pb = *(const f32x4*)(prow + k0 + 4);
            float hv0[8], hv1[8];
#pragma unroll
            for (int j = 0; j < 4; ++j) {
                hv0[j]     = fast_silu(pa[j] + lgA[ks][0][j]);
                hv0[4 + j] = fast_silu(pb[j] + lgA[ks][1][j]);
                hv1[j]     = fast_silu(pa[j] + lgB[ks][0][j]);
                hv1[4 + j] = fast_silu(pb[j] + lgB[ks][1][j]);
            }
            bf16x8 a0f = pack8_rhu(hv0);
            bf16x8 a1f = pack8_rhu(hv1);
#pragma unroll
            for (int nt = 0; nt < 4; ++nt)         // 8 independent MFMAs
                acc0[nt] = __builtin_amdgcn_mfma_f32_16x16x32_bf16(a0f, bfr[nt], acc0[nt], 0, 0, 0);
#pragma unroll
            for (int nt = 0; nt < 4; ++nt)
                acc1[nt] = __builtin_amdgcn_mfma_f32_16x16x32_bf16(a1f, bfr[nt], acc1[nt], 0, 0, 0);
        }

        // epilogues (b2 already in acc): lane holds D[m=q*4+r][n=nt*16+c]
#pragma unroll
        for (int at = 0; at < 2; ++at) {
            const f32x4* A = at ? acc1 : acc0;
            float s0 = 0.f, s1 = 0.f, s2 = 0.f, s3 = 0.f;
#pragma unroll
            for (int nt = 0; nt < 4; ++nt) {
                s0 += fast_silu(A[nt][0]) * w3f[nt];
                s1 += fast_silu(A[nt][1]) * w3f[nt];
                s2 += fast_silu(A[nt][2]) * w3f[nt];
                s3 += fast_silu(A[nt][3]) * w3f[nt];
            }
            s0 = rowsum16(s0);
            s1 = rowsum16(s1);
            s2 = rowsum16(s2);
            s3 = rowsum16(s3);
            if (c < 4) {
                float v = (c == 0) ? s0 : (c == 1) ? s1 : (c == 2) ? s2 : s3;
                const int e0 = (b * NLB + ih * 16 + i0 + at) * NPB + jt * JT_CHUNK;
                out[e0 + q * 4 + c] = fmaxf(v + b3v, 0.0f);
            }
        }
    }
}

// ---------------------------------------------------------------------------
extern "C" void kernel_launch(void* const* d_in, const int* in_sizes, int n_in,
                              void* d_out, int out_size, void* d_ws, size_t ws_size,
                              hipStream_t stream)
{
    const float* s_lig = (const float*)d_in[0];
    const float* s_poc = (const float*)d_in[1];
    const float* W1    = (const float*)d_in[4];
    const float* b1    = (const float*)d_in[5];
    const float* W2    = (const float*)d_in[6];
    const float* b2    = (const float*)d_in[7];
    const float* W3    = (const float*)d_in[8];
    const float* b3    = (const float*)d_in[9];

    (void)d_ws; (void)ws_size;   // Z workspace no longer needed

    hipLaunchKernelGGL(fused_kernel, dim3(B_CPLX * 20), dim3(256), 0, stream,
                       s_lig, s_poc, W1, b1, W2, b2, W3, b3, (float*)d_out);
}

// Round 2
// 141.580 us; speedup vs baseline: 1.2003x; 1.2003x over previous
//
#include <hip/hip_runtime.h>
#include <hip/hip_bf16.h>

// ---------------------------------------------------------------------------
// HiddenEdgeDistanceMLP on MI355X (gfx950)
//
// reference:  s = s_lig[l] + s_poc[p]          [E,256]
//             h1 = silu(s @ W1.T + b1)         [E,128]
//             h2 = silu(h1 @ W2.T + b2)        [E,64]
//             out = relu(h2 @ W3.T + b3)       [E]
//
// v14 (R1): revert R0's fusion (proj redundancy x3.3 + per-wave W1 conversion
//   made the fused kernel 98us vs 50+16 split; fixed harness overhead ~72us
//   identified). Two kernels again, edge restructured as a UNIFORM PERSISTENT
//   schedule to kill the batch-packing loss:
//    * item = (b, jt, atom-group g) = 8 atoms x 16 pockets; 5120 items.
//    * grid = 1024 blocks = exactly 4 blocks/CU x 256 CU; each block runs
//      exactly 5 consecutive items (5120/1024 = 5.0, perfectly uniform ->
//      no ceil(10/4)=3-batch 83% quantization; ~98% packing for R in {1,2,4}).
//    * W2 staged ONCE per block (1024 vs 2560 stagings).
//    * zp re-staged only when (b,jt) changes: exactly 1 interior re-stage
//      per block (ids 5k..5k+4 cross one multiple-of-4 boundary); barriers
//      only around that re-stage.
//    * next item's pocket regs loaded before the ks-loop, next ligand pair
//      loaded into dead lg buffers after the ks-loop (v12 prefetch idiom
//      extended across items).
//   Per-edge math BITWISE identical to v12 (silu, RHU pack, MFMA order,
//   DPP rowsum) -> absmax expected 0.001953125.
// v12 mechanisms kept: 2-atoms-per-K-pass, b2 folded into acc init, single
//   rhu-bf16 h1 + 1 MFMA/nt, W2 B-frags fragment-ordered in LDS, DPP rowsum,
//   perm packing, no min-waves bound (R3: VGPR cliff -> spills).
// ---------------------------------------------------------------------------

#define B_CPLX   128
#define NLB      32
#define NPB      160
#define SDIM     256
#define H1DIM    128
#define NL_TOT   (B_CPLX * NLB)         // 4096
#define NP_TOT   (B_CPLX * NPB)         // 20480
#define NROWS    (NL_TOT + NP_TOT)      // 24576
#define E_TOT    (B_CPLX * NLB * NPB)   // 655360

#define W1_LDS_STRIDE 264               // 256 + 8 bf16 pad
#define JT_CHUNK 16                     // pocket rows per item
#define ZP_STRIDE 132                   // 128 + 4 f32 pad

#define NITEMS        (B_CPLX * 10 * 4) // 5120 = b x jt x atom-group
#define NITEM_PER_BLK 5
#define EDGE_BLOCKS   (NITEMS / NITEM_PER_BLK)   // 1024 = 4/CU x 256 CU

typedef __bf16 bf16x8 __attribute__((ext_vector_type(8)));
typedef unsigned short ushortx8 __attribute__((ext_vector_type(8)));
typedef unsigned short ushortx4 __attribute__((ext_vector_type(4)));
typedef unsigned uintx4 __attribute__((ext_vector_type(4)));
typedef float f32x4 __attribute__((ext_vector_type(4)));

__device__ __forceinline__ unsigned short f2bf(float f) {
    unsigned u = __builtin_bit_cast(unsigned, f);
    u += 0x7FFFu + ((u >> 16) & 1u);          // round-to-nearest-even
    return (unsigned short)(u >> 16);
}

// v_perm_b32: pack hi16(x0) low, hi16(x1) high (1 op)
__device__ __forceinline__ unsigned perm_hi16u(unsigned u0, unsigned u1) {
    return __builtin_amdgcn_perm(u1, u0, 0x07060302u);
}

// round-half-up bf16 pair pack: bitpattern + 0x8000 then take hi16.
__device__ __forceinline__ unsigned pack2_rhu(float x0, float x1) {
    unsigned u0 = __builtin_bit_cast(unsigned, x0) + 0x8000u;
    unsigned u1 = __builtin_bit_cast(unsigned, x1) + 0x8000u;
    return perm_hi16u(u0, u1);
}

__device__ __forceinline__ bf16x8 pack8_rhu(const float* x) {
    uintx4 h;
#pragma unroll
    for (int j = 0; j < 4; ++j) h[j] = pack2_rhu(x[2 * j], x[2 * j + 1]);
    return __builtin_bit_cast(bf16x8, h);
}

// hi/lo exact split (proj only): hi = trunc bf16, lo = bf16(x - hi)
__device__ __forceinline__ void pack_split(const float* x, bf16x8& hi, bf16x8& lo) {
    uintx4 h, l;
#pragma unroll
    for (int j = 0; j < 4; ++j) {
        float x0 = x[2 * j], x1 = x[2 * j + 1];
        unsigned u0 = __builtin_bit_cast(unsigned, x0);
        unsigned u1 = __builtin_bit_cast(unsigned, x1);
        h[j] = perm_hi16u(u0, u1);
        float hf0 = __builtin_bit_cast(float, u0 & 0xFFFF0000u);
        float hf1 = __builtin_bit_cast(float, u1 & 0xFFFF0000u);
        l[j] = pack2_rhu(x0 - hf0, x1 - hf1);
    }
    hi = __builtin_bit_cast(bf16x8, h);
    lo = __builtin_bit_cast(bf16x8, l);
}

__device__ __forceinline__ float fast_silu(float x) {
    return x * __builtin_amdgcn_rcpf(1.0f + __expf(-x));
}

// full-rate 16-lane row reduction: v_add_f32 + dpp row_ror 1,2,4,8
__device__ __forceinline__ float rowsum16(float s) {
    int b;
    b = __builtin_bit_cast(int, s);
    b = __builtin_amdgcn_update_dpp(b, b, 0x121, 0xF, 0xF, false);  // ror:1
    s += __builtin_bit_cast(float, b);
    b = __builtin_bit_cast(int, s);
    b = __builtin_amdgcn_update_dpp(b, b, 0x122, 0xF, 0xF, false);  // ror:2
    s += __builtin_bit_cast(float, b);
    b = __builtin_bit_cast(int, s);
    b = __builtin_amdgcn_update_dpp(b, b, 0x124, 0xF, 0xF, false);  // ror:4
    s += __builtin_bit_cast(float, b);
    b = __builtin_bit_cast(int, s);
    b = __builtin_amdgcn_update_dpp(b, b, 0x128, 0xF, 0xF, false);  // ror:8
    s += __builtin_bit_cast(float, b);
    return s;
}

// ---------------------------------------------------------------------------
// Kernel 1: Z[m][n] = X[m] @ W1[n] (+ b1[n] if m is a ligand row)
//   768 blocks = 384 row-tile groups x 2 N-halves; hi/lo split -> Z ~exact.
//   (verbatim v12)
// ---------------------------------------------------------------------------
__global__ __launch_bounds__(256) void proj_kernel(
    const float* __restrict__ s_lig, const float* __restrict__ s_poc,
    const float* __restrict__ W1,    const float* __restrict__ b1,
    float* __restrict__ Z)
{
    __shared__ unsigned short w1s[64 * W1_LDS_STRIDE];   // 33.8 KB

    const int tid  = threadIdx.x;
    const int tg   = blockIdx.x >> 1;             // row-tile group 0..383
    const int half = blockIdx.x & 1;              // N half

    {
        const f32x4* w4 = (const f32x4*)(W1 + (size_t)half * 64 * SDIM);  // 4096 units
#pragma unroll
        for (int r = 0; r < 2; ++r) {
            f32x4 t[8];
#pragma unroll
            for (int s = 0; s < 8; ++s) t[s] = w4[tid + (r * 8 + s) * 256];
#pragma unroll
            for (int s = 0; s < 8; ++s) {
                const int u = tid + (r * 8 + s) * 256;
                const int n = u >> 6;             // 64 f32x4 per 256-col row
                const int k4 = u & 63;
                ushortx4 us;
#pragma unroll
                for (int j = 0; j < 4; ++j) us[j] = f2bf(t[s][j]);
                *(ushortx4*)(&w1s[n * W1_LDS_STRIDE + k4 * 4]) = us;
            }
        }
    }
    __syncthreads();

    const int lane = tid & 63;
    const int widx = tid >> 6;
    const int c    = lane & 15;
    const int q    = lane >> 4;
    const int tile = tg * 4 + widx;               // 0..1535
    const int row  = tile * 16 + c;

    const float* src = (row < NL_TOT) ? (s_lig + (size_t)row * SDIM)
                                      : (s_poc + (size_t)(row - NL_TOT) * SDIM);

    f32x4 acc[4];
#pragma unroll
    for (int nt = 0; nt < 4; ++nt) acc[nt] = (f32x4){0.f, 0.f, 0.f, 0.f};

#pragma unroll
    for (int ks = 0; ks < 8; ++ks) {              // K = 256 = 8 x 32
        const int k0 = ks * 32 + q * 8;
        f32x4 xa = *reinterpret_cast<const f32x4*>(src + k0);
        f32x4 xb = *reinterpret_cast<const f32x4*>(src + k0 + 4);
        float xv[8] = {xa[0], xa[1], xa[2], xa[3], xb[0], xb[1], xb[2], xb[3]};
        bf16x8 ahi, alo;
        pack_split(xv, ahi, alo);
        bf16x8 bfrag[4];
#pragma unroll
        for (int nt = 0; nt < 4; ++nt)
            bfrag[nt] = *reinterpret_cast<const bf16x8*>(
                &w1s[(nt * 16 + c) * W1_LDS_STRIDE + k0]);
#pragma unroll
        for (int nt = 0; nt < 4; ++nt)            // hi pass (dep distance 4)
            acc[nt] = __builtin_amdgcn_mfma_f32_16x16x32_bf16(ahi, bfrag[nt], acc[nt], 0, 0, 0);
#pragma unroll
        for (int nt = 0; nt < 4; ++nt)            // lo pass
            acc[nt] = __builtin_amdgcn_mfma_f32_16x16x32_bf16(alo, bfrag[nt], acc[nt], 0, 0, 0);
    }

    // C/D layout: col n' = lane&15, row m = q*4 + reg
    const int mb = tile * 16 + q * 4;
#pragma unroll
    for (int nt = 0; nt < 4; ++nt) {
        const int n = half * 64 + nt * 16 + c;
        const float bias = b1[n];
#pragma unroll
        for (int r = 0; r < 4; ++r) {
            const int m = mb + r;
            float v = acc[nt][r];
            if (m < NL_TOT) v += bias;            // fold b1 into ligand rows only
            Z[(size_t)m * H1DIM + n] = v;
        }
    }
}

// ---------------------------------------------------------------------------
// Kernel 2 (persistent-uniform): 1024 blocks x 5 items.
//   item id = ((b*10 + jt)*4 + g): complex b, pocket chunk jt, atom group g
//   (8 atoms). 4 waves x 1 pair (2 atoms) per item, v12 pair body verbatim.
// ---------------------------------------------------------------------------
__global__ __launch_bounds__(256) void edge_kernel(
    const float* __restrict__ Z,
    const float* __restrict__ W2, const float* __restrict__ b2,
    const float* __restrict__ W3, const float* __restrict__ b3,
    float* __restrict__ out)
{
    __shared__ float zp[JT_CHUNK * ZP_STRIDE];            // 8.4 KB
    __shared__ unsigned short w2s[16 * 64 * 8];           // 16 KB frag-ordered

    const int tid = threadIdx.x;

    // stage W2 as bf16 B-fragments, fragment-ordered (ONCE per block):
    //   slot = chunk*64 + lane, chunk = nt*4 + ks;
    //   frag(lane) = W2[n = nt*16 + (lane&15)][ks*32 + (lane>>4)*8 .. +8]
    {
#pragma unroll
        for (int s = 0; s < 4; ++s) {
            const int slot   = tid + s * 256;             // 0..1023
            const int lane_s = slot & 63;
            const int chunk  = slot >> 6;
            const int nt     = chunk >> 2;
            const int ks     = chunk & 3;
            const int n      = nt * 16 + (lane_s & 15);
            const int k0     = ks * 32 + (lane_s >> 4) * 8;
            const float* wsrc = W2 + (size_t)n * H1DIM + k0;
            f32x4 wa = *(const f32x4*)wsrc;
            f32x4 wb = *(const f32x4*)(wsrc + 4);
            float wv[8] = {wa[0], wa[1], wa[2], wa[3], wb[0], wb[1], wb[2], wb[3]};
            ushortx8 us;
#pragma unroll
            for (int j = 0; j < 8; ++j) us[j] = f2bf(wv[j]);   // RNE for weights
            *(ushortx8*)(&w2s[slot * 8]) = us;
        }
    }

    const int lane = tid & 63;
    const int widx = tid >> 6;
    const int c    = lane & 15;
    const int q    = lane >> 4;

    float b2f[4], w3f[4];
#pragma unroll
    for (int nt = 0; nt < 4; ++nt) {
        b2f[nt] = b2[nt * 16 + c];
        w3f[nt] = W3[nt * 16 + c];
    }
    const float b3v = b3[0];

    // ---- item schedule: 5 consecutive ids starting at blockIdx*5 ----
    int id = blockIdx.x * NITEM_PER_BLK;
    int b  = id / 40;
    int rr = id - b * 40;
    int jt = rr >> 2;                             // 0..9
    int g  = rr & 3;                              // atom group: atoms g*8..g*8+7

    const int u0 = tid, u1 = tid + 256;

    // pocket rows for item 0: load regs + LDS write before the single barrier
    f32x4 zr0, zr1;
    {
        const float* zpg = Z + (size_t)(NL_TOT + b * NPB + jt * JT_CHUNK) * H1DIM;
        zr0 = *(const f32x4*)(zpg + (size_t)(u0 >> 5) * H1DIM + (u0 & 31) * 4);
        zr1 = *(const f32x4*)(zpg + (size_t)(u1 >> 5) * H1DIM + (u1 & 31) * 4);
        *(f32x4*)(&zp[(u0 >> 5) * ZP_STRIDE + (u0 & 31) * 4]) = zr0;
        *(f32x4*)(&zp[(u1 >> 5) * ZP_STRIDE + (u1 & 31) * 4]) = zr1;
    }

    // ligand pair rows for item 0 (wave widx: atoms g*8 + widx*2, +1)
    f32x4 lgA[4][2], lgB[4][2];
    {
        const float* lr0 = Z + (size_t)(b * NLB + g * 8 + widx * 2) * H1DIM;
#pragma unroll
        for (int ks = 0; ks < 4; ++ks) {
            const int k0 = ks * 32 + q * 8;
            lgA[ks][0] = *(const f32x4*)(lr0 + k0);
            lgA[ks][1] = *(const f32x4*)(lr0 + k0 + 4);
            lgB[ks][0] = *(const f32x4*)(lr0 + H1DIM + k0);
            lgB[ks][1] = *(const f32x4*)(lr0 + H1DIM + k0 + 4);
        }
    }

    __syncthreads();   // W2 + zp(item0) visible

    const float* prow = &zp[c * ZP_STRIDE];
    const unsigned short* wbase = &w2s[lane * 8];          // + chunk*512 ushorts

    for (int it = 0; it < NITEM_PER_BLK; ++it) {
        // decode next item; prefetch its pocket regs if (b,jt) changes.
        // All of bn/jtn/gn/sc are block-uniform (derived from blockIdx+it).
        int bn = b, jtn = jt, gn = g;
        bool sc = false;
        if (it < NITEM_PER_BLK - 1) {
            const int idn = id + 1;
            bn = idn / 40;
            const int rn = idn - bn * 40;
            jtn = rn >> 2;
            gn  = rn & 3;
            sc  = (jtn != jt) || (bn != b);       // exactly once per block
            if (sc) {
                const float* zpg = Z + (size_t)(NL_TOT + bn * NPB + jtn * JT_CHUNK) * H1DIM;
                zr0 = *(const f32x4*)(zpg + (size_t)(u0 >> 5) * H1DIM + (u0 & 31) * 4);
                zr1 = *(const f32x4*)(zpg + (size_t)(u1 >> 5) * H1DIM + (u1 & 31) * 4);
            }
        }

        // b2 folded into acc init (saves epilogue adds)
        f32x4 acc0[4], acc1[4];
#pragma unroll
        for (int nt = 0; nt < 4; ++nt) {
            const float bb = b2f[nt];
            acc0[nt] = (f32x4){bb, bb, bb, bb};
            acc1[nt] = (f32x4){bb, bb, bb, bb};
        }

#pragma unroll
        for (int ks = 0; ks < 4; ++ks) {           // K = 128 = 4 x 32
            const int k0 = ks * 32 + q * 8;
            bf16x8 bfr[4];
#pragma unroll
            for (int nt = 0; nt < 4; ++nt)         // conflict-free ds_read_b128
                bfr[nt] = *(const bf16x8*)(wbase + (nt * 4 + ks) * 512);
            f32x4 pa = *(const f32x4*)(prow + k0);
            f32x4 pb = *(const f32x4*)(prow + k0 + 4);
            float hv0[8], hv1[8];
#pragma unroll
            for (int j = 0; j < 4; ++j) {
                hv0[j]     = fast_silu(pa[j] + lgA[ks][0][j]);
                hv0[4 + j] = fast_silu(pb[j] + lgA[ks][1][j]);
                hv1[j]     = fast_silu(pa[j] + lgB[ks][0][j]);
                hv1[4 + j] = fast_silu(pb[j] + lgB[ks][1][j]);
            }
            bf16x8 a0f = pack8_rhu(hv0);
            bf16x8 a1f = pack8_rhu(hv1);
#pragma unroll
            for (int nt = 0; nt < 4; ++nt)         // 8 independent MFMAs
                acc0[nt] = __builtin_amdgcn_mfma_f32_16x16x32_bf16(a0f, bfr[nt], acc0[nt], 0, 0, 0);
#pragma unroll
            for (int nt = 0; nt < 4; ++nt)
                acc1[nt] = __builtin_amdgcn_mfma_f32_16x16x32_bf16(a1f, bfr[nt], acc1[nt], 0, 0, 0);
        }

        // prefetch next item's ligand pair into the now-dead lg buffers
        // (latency hidden under the epilogue + re-stage barriers)
        if (it < NITEM_PER_BLK - 1) {
            const float* lrn = Z + (size_t)(bn * NLB + gn * 8 + widx * 2) * H1DIM;
#pragma unroll
            for (int ks = 0; ks < 4; ++ks) {
                const int k0 = ks * 32 + q * 8;
                lgA[ks][0] = *(const f32x4*)(lrn + k0);
                lgA[ks][1] = *(const f32x4*)(lrn + k0 + 4);
                lgB[ks][0] = *(const f32x4*)(lrn + H1DIM + k0);
                lgB[ks][1] = *(const f32x4*)(lrn + H1DIM + k0 + 4);
            }
        }

        // epilogues (b2 already in acc): lane holds D[m=q*4+r][n=nt*16+c]
#pragma unroll
        for (int at = 0; at < 2; ++at) {
            const f32x4* A = at ? acc1 : acc0;
            float s0 = 0.f, s1 = 0.f, s2 = 0.f, s3 = 0.f;
#pragma unroll
            for (int nt = 0; nt < 4; ++nt) {
                s0 += fast_silu(A[nt][0]) * w3f[nt];
                s1 += fast_silu(A[nt][1]) * w3f[nt];
                s2 += fast_silu(A[nt][2]) * w3f[nt];
                s3 += fast_silu(A[nt][3]) * w3f[nt];
            }
            s0 = rowsum16(s0);
            s1 = rowsum16(s1);
            s2 = rowsum16(s2);
            s3 = rowsum16(s3);
            if (c < 4) {
                float v = (c == 0) ? s0 : (c == 1) ? s1 : (c == 2) ? s2 : s3;
                const int e0 = (b * NLB + g * 8 + widx * 2 + at) * NPB + jt * JT_CHUNK;
                out[e0 + q * 4 + c] = fmaxf(v + b3v, 0.0f);
            }
        }

        // re-stage pocket rows only when (b,jt) changes (block-uniform branch):
        // barrier 1 = all waves done reading zp; barrier 2 = new zp visible.
        if (sc) {
            __syncthreads();
            *(f32x4*)(&zp[(u0 >> 5) * ZP_STRIDE + (u0 & 31) * 4]) = zr0;
            *(f32x4*)(&zp[(u1 >> 5) * ZP_STRIDE + (u1 & 31) * 4]) = zr1;
            __syncthreads();
        }

        id += 1; b = bn; jt = jtn; g = gn;
    }
}

// ---------------------------------------------------------------------------
extern "C" void kernel_launch(void* const* d_in, const int* in_sizes, int n_in,
                              void* d_out, int out_size, void* d_ws, size_t ws_size,
                              hipStream_t stream)
{
    const float* s_lig = (const float*)d_in[0];
    const float* s_poc = (const float*)d_in[1];
    const float* W1    = (const float*)d_in[4];
    const float* b1    = (const float*)d_in[5];
    const float* W2    = (const float*)d_in[6];
    const float* b2    = (const float*)d_in[7];
    const float* W3    = (const float*)d_in[8];
    const float* b3    = (const float*)d_in[9];

    float* Z = (float*)d_ws;   // NROWS*H1DIM*4 = 12.58 MB workspace

    hipLaunchKernelGGL(proj_kernel, dim3(NROWS / 16 / 4 * 2), dim3(256), 0, stream,
                       s_lig, s_poc, W1, b1, Z);
    hipLaunchKernelGGL(edge_kernel, dim3(EDGE_BLOCKS), dim3(256), 0, stream,
                       Z, W2, b2, W3, b3, (float*)d_out);
}